// Round 3
// baseline (304.840 us; speedup 1.0000x reference)
//
#include <hip/hip_runtime.h>
#include <math.h>
#include <stdint.h>

// VectorQuantizer on MI355X (gfx950). N=131072, D=64, K=2048, fp32.
// Strategy: bf16 MFMA approx scores (error-bounded) -> margin-pruned exact
// fp32 rescore -> exact argmin. out: [N*D] quantized_st | [1] loss | [N] idx.
//
// ws layout (bytes), total ~792 KB (assumed ws_size >= 1 MB):
//   [0      ] double partials[1024]
//   [8192   ] float  en2[K]        (||l2norm(emb)_k||^2)
//   [16384  ] float  c0[K]         (-0.5*en2, MFMA C-init)
//   [24576  ] float  en[K*64]      (l2norm(emb))
//   [548864 ] u32    frags[K*64/2] (bf16 A-fragments, MFMA layout, 256 KB)

#define D 64
#define EPS 1e-12f
#define WPB 8              // waves per block
#define RPW 16             // rows per wave (MFMA N)
#define RPB (WPB * RPW)    // 128 rows per block
#define CHUNK_TILES 16     // codes-tiles staged per chunk (16 tiles = 32 KB)
#define CAND_CAP 120
#define MARGIN 0.010f      // > 2 * (2^-8 + slop) worst-case bf16 approx error

typedef short bf16x8 __attribute__((ext_vector_type(8)));
typedef float f32x4 __attribute__((ext_vector_type(4)));

__device__ __forceinline__ uint32_t f2bf(float f) {   // RNE f32->bf16 (finite)
    uint32_t u = __builtin_bit_cast(uint32_t, f);
    return (u + 0x7FFFu + ((u >> 16) & 1u)) >> 16;
}

// ---------------- Kernel A: normalize codebook ----------------
__global__ __launch_bounds__(256) void vq_norm_emb(const float* __restrict__ emb,
                                                   float* __restrict__ en,
                                                   float* __restrict__ en2,
                                                   float* __restrict__ c0,
                                                   int K) {
    int wave = (int)((blockIdx.x * blockDim.x + threadIdx.x) >> 6);
    int lane = threadIdx.x & 63;
    if (wave >= K) return;
    float v = emb[(size_t)wave * D + lane];
    float s = v * v;
    #pragma unroll
    for (int m = 32; m >= 1; m >>= 1) s += __shfl_xor(s, m, 64);
    float e = v / fmaxf(sqrtf(s), EPS);          // division: F.normalize fidelity
    float s2 = e * e;
    #pragma unroll
    for (int m = 32; m >= 1; m >>= 1) s2 += __shfl_xor(s2, m, 64);
    en[(size_t)wave * D + lane] = e;
    if (lane == 0) { en2[wave] = s2; c0[wave] = -0.5f * s2; }
}

// ---------------- Kernel A2: build bf16 A-fragments ----------------
// Tile t covers codes [t*16, t*16+16). Fragment for (t, half h, lane l):
// code = t*16 + (l&15), dims = h*32 + (l>>4)*8 + j, j=0..7 packed low->high.
// Stored 16 B per lane, contiguous: byte off = ((t*2+h)*64 + l)*16.
__global__ __launch_bounds__(256) void vq_build_frags(const float* __restrict__ en,
                                                      uint32_t* __restrict__ frags,
                                                      int K) {
    int t = (int)(blockIdx.x * blockDim.x + threadIdx.x);
    int tile = t >> 6, lane = t & 63;
    if (tile >= K / 16) return;
    int code = tile * 16 + (lane & 15);
    int dbase = (lane >> 4) * 8;
    #pragma unroll
    for (int h = 0; h < 2; ++h) {
        const float* p = en + (size_t)code * D + h * 32 + dbase;
        uint4 u;
        u.x = f2bf(p[0]) | (f2bf(p[1]) << 16);
        u.y = f2bf(p[2]) | (f2bf(p[3]) << 16);
        u.z = f2bf(p[4]) | (f2bf(p[5]) << 16);
        u.w = f2bf(p[6]) | (f2bf(p[7]) << 16);
        *(uint4*)(frags + ((size_t)(tile * 2 + h) * 64 + lane) * 4) = u;
    }
}

// ---------------- Kernel B: main ----------------
__global__ __launch_bounds__(512, 2) void vq_main(const float* __restrict__ x,
                                                  const float* __restrict__ en,
                                                  const float* __restrict__ en2g,
                                                  const float* __restrict__ c0g,
                                                  const uint32_t* __restrict__ frags,
                                                  float* __restrict__ out_q,
                                                  float* __restrict__ out_idx,
                                                  double* __restrict__ partials,
                                                  int N, int K) {
    __shared__ __align__(16) float xn[WPB][RPW][68];                 // 34.8 KB (pad 68)
    __shared__ __align__(16) float c0l[2048];                        // 8 KB
    __shared__ __align__(16) uint32_t fragbuf[2][CHUNK_TILES * 512]; // 2 x 32 KB
    __shared__ uint32_t cand[WPB][CAND_CAP];
    __shared__ int candcnt[WPB];
    __shared__ unsigned long long keys[RPB];
    __shared__ double red[WPB];

    const int tid = (int)threadIdx.x;
    const int w = tid >> 6, lane = tid & 63;
    const int rowbase = (int)blockIdx.x * RPB + w * RPW;
    const int NT = K / 16;                    // 128 tiles
    const int NC = NT / CHUNK_TILES;          // 8 chunks

    // ---- phase 0: x load + normalize; stage c0; init keys/cand ----
    for (int r = 0; r < RPW; ++r) {
        float v = x[(size_t)(rowbase + r) * D + lane];
        float s = v * v;
        #pragma unroll
        for (int m = 32; m >= 1; m >>= 1) s += __shfl_xor(s, m, 64);
        xn[w][r][lane] = v / fmaxf(sqrtf(s), EPS);
    }
    for (int i = tid; i < K; i += WPB * 64) c0l[i] = c0g[i];
    for (int i = tid; i < RPB; i += WPB * 64) keys[i] = ~0ull;
    if (lane == 0) candcnt[w] = 0;
    __syncthreads();

    // ---- B-fragments (persist in regs): col = lane&15 = local row ----
    bf16x8 bfr[2];
    #pragma unroll
    for (int h = 0; h < 2; ++h) {
        const float* p = &xn[w][lane & 15][h * 32 + ((lane >> 4) * 8)];
        union { uint32_t u[4]; bf16x8 v; } cvt;
        cvt.u[0] = f2bf(p[0]) | (f2bf(p[1]) << 16);
        cvt.u[1] = f2bf(p[2]) | (f2bf(p[3]) << 16);
        cvt.u[2] = f2bf(p[4]) | (f2bf(p[5]) << 16);
        cvt.u[3] = f2bf(p[6]) | (f2bf(p[7]) << 16);
        bfr[h] = cvt.v;
    }

    // ---- passes: 0 = find row-max approx score, 1 = collect candidates ----
    // R = dot(xn_bf, en_bf) - 0.5*en2  (argmin d == argmax R; xn2 cancels).
    // Pass-1 R is bit-identical (same data flow) so threshold test is sound.
    float Rmax = -3.0e38f;
    float tau = 0.0f;
    const float4* frags4 = (const float4*)frags;

    for (int pass = 0; pass < 2; ++pass) {
        if (pass == 1) {
            float r1 = fmaxf(Rmax, __shfl_xor(Rmax, 16, 64));
            float r2 = fmaxf(r1, __shfl_xor(r1, 32, 64));
            tau = r2 - MARGIN;                 // row-best (over 4 lanes) - margin
        }
        // prologue: stage chunk 0
        float4 st[4];
        #pragma unroll
        for (int i = 0; i < 4; ++i) st[i] = frags4[tid + i * 512];
        #pragma unroll
        for (int i = 0; i < 4; ++i) *(float4*)&fragbuf[0][(tid + i * 512) * 4] = st[i];
        __syncthreads();

        int buf = 0;
        for (int c = 0; c < NC; ++c) {
            if (c + 1 < NC) {                  // prefetch next chunk into regs
                #pragma unroll
                for (int i = 0; i < 4; ++i)
                    st[i] = frags4[(size_t)(c + 1) * 2048 + tid + i * 512];
            }
            #pragma unroll 4
            for (int tl = 0; tl < CHUNK_TILES; ++tl) {
                int t = c * CHUNK_TILES + tl;
                int cb = t * 16 + ((lane >> 4) << 2);
                f32x4 acc = *(const f32x4*)&c0l[cb];   // C-init = -0.5*en2[code]
                bf16x8 a0 = *(const bf16x8*)&fragbuf[buf][(tl * 2 + 0) * 256 + lane * 4];
                bf16x8 a1 = *(const bf16x8*)&fragbuf[buf][(tl * 2 + 1) * 256 + lane * 4];
                acc = __builtin_amdgcn_mfma_f32_16x16x32_bf16(a0, bfr[0], acc, 0, 0, 0);
                acc = __builtin_amdgcn_mfma_f32_16x16x32_bf16(a1, bfr[1], acc, 0, 0, 0);
                float m4 = fmaxf(fmaxf(acc[0], acc[1]), fmaxf(acc[2], acc[3]));
                if (pass == 0) {
                    Rmax = fmaxf(Rmax, m4);
                } else if (__any(m4 >= tau)) {  // rare (~15% of tiles)
                    #pragma unroll
                    for (int q = 0; q < 4; ++q) {
                        if (acc[q] >= tau) {
                            int slot = atomicAdd(&candcnt[w], 1);
                            if (slot < CAND_CAP)
                                cand[w][slot] = ((uint32_t)(cb + q) << 4) | (uint32_t)(lane & 15);
                        }
                    }
                }
            }
            if (c + 1 < NC) {                  // write prefetched chunk
                buf ^= 1;
                #pragma unroll
                for (int i = 0; i < 4; ++i) *(float4*)&fragbuf[buf][(tid + i * 512) * 4] = st[i];
            }
            __syncthreads();
        }
    }

    // ---- phase 3: exact fp32 rescore of candidates (wave-local list) ----
    int cnt = candcnt[w];
    cnt = cnt < CAND_CAP ? cnt : CAND_CAP;
    for (int base = 0; base < cnt; base += 64) {
        int i = base + lane;
        if (i < cnt) {
            uint32_t e = cand[w][i];
            int k = (int)(e >> 4), r4 = (int)(e & 15u);
            const float* ev = en + (size_t)k * D;
            float dot = 0.f;
            #pragma unroll
            for (int d0 = 0; d0 < D; ++d0) dot = fmaf(xn[w][r4][d0], ev[d0], dot);
            float R = fmaf(-0.5f, en2g[k], dot);
            uint32_t fb = __builtin_bit_cast(uint32_t, -R);   // minimize -R
            uint32_t ord = (fb & 0x80000000u) ? ~fb : (fb | 0x80000000u);
            unsigned long long key = ((unsigned long long)ord << 32) | (uint32_t)k;
            atomicMin(&keys[w * RPW + r4], key);              // ties -> smaller k
        }
    }
    __syncthreads();

    // ---- phase 4: epilogue (gather, renormalize, ST output, loss) ----
    float ls = 0.f;
    for (int r = 0; r < RPW; ++r) {
        int k = (int)(keys[w * RPW + r] & 0x7FFull);   // bounded even on overflow
        float rn = fmaxf(sqrtf(en2g[k]), EPS);
        float q = en[(size_t)k * D + lane] / rn;       // l2norm(en[k]) exactly
        float a = xn[w][r][lane];
        float dx = q - a;
        ls = fmaf(dx, dx, ls);
        out_q[(size_t)(rowbase + r) * D + lane] = a + dx;   // xn + (quantized - xn)
        if (lane == 0) out_idx[rowbase + r] = (float)k;
    }
    #pragma unroll
    for (int m = 32; m >= 1; m >>= 1) ls += __shfl_xor(ls, m, 64);
    if (lane == 0) red[w] = (double)ls;
    __syncthreads();
    if (tid == 0) {
        double s = 0.0;
        #pragma unroll
        for (int i = 0; i < WPB; ++i) s += red[i];
        partials[blockIdx.x] = s;
    }
}

// ---------------- Kernel C: finalize loss ----------------
__global__ __launch_bounds__(512) void vq_finalize(const double* __restrict__ partials,
                                                   int nb, float* __restrict__ loss_out,
                                                   int N) {
    __shared__ double red[512];
    int t = (int)threadIdx.x;
    double s = 0.0;
    for (int i = t; i < nb; i += 512) s += partials[i];
    red[t] = s;
    __syncthreads();
    #pragma unroll
    for (int off = 256; off >= 1; off >>= 1) {
        if (t < off) red[t] += red[t + off];
        __syncthreads();
    }
    if (t == 0) {
        double mean = red[0] / ((double)N * (double)D);
        loss_out[0] = (float)(mean * 1.25);   // q_loss + 0.25*e_loss (identical terms)
    }
}

extern "C" void kernel_launch(void* const* d_in, const int* in_sizes, int n_in,
                              void* d_out, int out_size, void* d_ws, size_t ws_size,
                              hipStream_t stream) {
    const float* x   = (const float*)d_in[0];
    const float* emb = (const float*)d_in[1];
    int N = in_sizes[0] / D;
    int K = in_sizes[1] / D;

    float* out      = (float*)d_out;
    float* out_q    = out;
    float* loss_out = out + (size_t)N * D;
    float* out_idx  = out + (size_t)N * D + 1;

    char* ws = (char*)d_ws;
    double*   partials = (double*)ws;                       // 8 KB
    float*    en2      = (float*)(ws + 8192);               // 8 KB
    float*    c0       = (float*)(ws + 16384);              // 8 KB
    float*    en       = (float*)(ws + 24576);              // 512 KB
    uint32_t* frags    = (uint32_t*)(ws + 548864);          // 256 KB

    vq_norm_emb<<<(K + 3) / 4, 256, 0, stream>>>(emb, en, en2, c0, K);
    vq_build_frags<<<(K / 16 * 64 + 255) / 256, 256, 0, stream>>>(en, frags, K);

    int nbB = N / RPB;   // 1024
    vq_main<<<nbB, 512, 0, stream>>>(x, en, en2, c0, frags, out_q, out_idx,
                                     partials, N, K);
    vq_finalize<<<1, 512, 0, stream>>>(partials, nbB, loss_out, N);
}